// Round 5
// baseline (279.442 us; speedup 1.0000x reference)
//
#include <hip/hip_runtime.h>
#include <hip/hip_bf16.h>

#define N_Q 256
#define M_S 1024
#define DD 512
#define HH 512

typedef __attribute__((ext_vector_type(8))) short short8;
typedef __attribute__((ext_vector_type(8))) __bf16 bf16x8;
typedef __attribute__((ext_vector_type(16))) float f32x16;
typedef __attribute__((ext_vector_type(2))) __bf16 bf16x2;

union U8 { short8 s; bf16x8 b; };

__device__ __forceinline__ unsigned short f2bf(float f) {
  unsigned int u = __float_as_uint(f);
  u += 0x7FFFu + ((u >> 16) & 1u);
  return (unsigned short)(u >> 16);
}

__device__ __forceinline__ short8 pack8(const float* d) {
#if defined(__has_builtin) && __has_builtin(__builtin_amdgcn_cvt_pk_bf16_f32)
  short8 r;
#pragma unroll
  for (int i = 0; i < 4; ++i) {
    union { bf16x2 v; short s[2]; } u;
    u.v = __builtin_amdgcn_cvt_pk_bf16_f32(d[2 * i], d[2 * i + 1]);
    r[2 * i] = u.s[0];
    r[2 * i + 1] = u.s[1];
  }
  return r;
#else
  short8 r;
#pragma unroll
  for (int i = 0; i < 8; ++i) r[i] = (short)f2bf(d[i]);
  return r;
#endif
}

__device__ __forceinline__ short8 packdiff(float4 e0, float4 e1, float4 s0, float4 s1) {
  float d[8];
  d[0] = fabsf(e0.x - s0.x); d[1] = fabsf(e0.y - s0.y);
  d[2] = fabsf(e0.z - s0.z); d[3] = fabsf(e0.w - s0.w);
  d[4] = fabsf(e1.x - s1.x); d[5] = fabsf(e1.y - s1.y);
  d[6] = fabsf(e1.z - s1.z); d[7] = fabsf(e1.w - s1.w);
  return pack8(d);
}

// W1 [D][H] fp32 -> w1s in MFMA-B-fragment order (verified R3/R4).
// Frag f = kc*16 + h32; elem (lane l, j) = W1[kc*16 + (l>>5)*8 + j][h32*32 + (l&31)].
__global__ __launch_bounds__(512) void prep_w1s(const float* __restrict__ W1,
                                                unsigned short* __restrict__ w1s) {
  const int f = blockIdx.x;            // 0..511
  const int kc = f >> 4, h32 = f & 15;
  const int l = threadIdx.x & 63, j = threadIdx.x >> 6;
  const int h = h32 * 32 + (l & 31);
  const int k = kc * 16 + (l >> 5) * 8 + j;
  w1s[f * 512 + l * 8 + j] = f2bf(W1[k * HH + h]);
}

// Block: 256 thr = 4 waves. Tile 128 pairs (8n x 16m) x 256 h (z-split) x K=512.
// A tile LDS-staged in two K=256 halves (64 KB). B register-direct from w1s,
// 2-step lookahead. Wave tile 128p x 64h: acc[4 am][2 tj]. 2 blocks/CU.
// Partial logits atomicAdd'ed into zeroed out; finalized by logits_finalize.
__global__ __launch_bounds__(256, 2) void support_kernel(
    const float* __restrict__ emb, const float* __restrict__ sup,
    const unsigned short* __restrict__ w1s, const float* __restrict__ b1,
    const float* __restrict__ W2, float* __restrict__ out) {
  __shared__ short As[128 * 256];  // 64 KB; psums aliased post-loop

  const int tid = threadIdx.x;
  const int lane = tid & 63;
  const int wid = tid >> 6;        // 0..3 : 64-h slice
  const int l31 = lane & 31;
  const int khalf = lane >> 5;
  const int ax = l31 & 7;          // read-side chunk XOR

  const int m0 = blockIdx.x * 16;
  const int n0 = blockIdx.y * 8;
  const int hz8 = blockIdx.z * 8;  // h32 base of this block's 256-h slice

  // B fragment base: h32 = hz8 + wid*2 + tj; frag (ks,tj) at +(ks*16+tj)*512
  const unsigned short* bb = w1s + (hz8 + wid * 2) * 512 + lane * 8;

  // staging map: c = k-chunk of 8 (0..31 per half), nl = n_local (0..7)
  const int c = tid & 31;
  const int nl = tid >> 5;
  const float* ep_ = emb + (n0 + nl) * DD + c * 8;
  const float* sp_ = sup + m0 * DD + c * 8;

  f32x16 acc[4][2] = {};
  U8 a[2][4], b[3][2];

  // B prefetch for global steps 0,1 (in flight during staging)
#pragma unroll
  for (int tj = 0; tj < 2; ++tj) {
    b[0][tj].s = *(const short8*)(bb + (0 * 16 + tj) * 512);
    b[1][tj].s = *(const short8*)(bb + (1 * 16 + tj) * 512);
  }

#pragma unroll
  for (int half = 0; half < 2; ++half) {
    // ---- stage 128p x 256k diff tile, chunks XOR-swizzled by (p&7) ----
    {
      const float4 e0 = *(const float4*)(ep_ + half * 256);
      const float4 e1 = *(const float4*)(ep_ + half * 256 + 4);
#pragma unroll
      for (int m = 0; m < 16; ++m) {
        const float* sp = sp_ + m * DD + half * 256;
        const float4 s0 = *(const float4*)sp;
        const float4 s1 = *(const float4*)(sp + 4);
        const int p = nl * 16 + m;           // (p&7) == (m&7)
        *(short8*)&As[p * 256 + ((c ^ (m & 7)) * 8)] = packdiff(e0, e1, s0, s1);
      }
    }
    __syncthreads();

    // A prologue for kc=0 of this half
#pragma unroll
    for (int am = 0; am < 4; ++am)
      a[0][am].s = *(const short8*)&As[(am * 32 + l31) * 256 + ((khalf ^ ax) * 8)];

#pragma unroll
    for (int kc = 0; kc < 16; ++kc) {
      const int ks = half * 16 + kc;         // global K-step
      const int cur = kc & 1, nxt = cur ^ 1;
      if (kc < 15) {                         // A lookahead (LDS)
        const int cc = (((kc + 1) * 2 + khalf) ^ ax) * 8;
#pragma unroll
        for (int am = 0; am < 4; ++am)
          a[nxt][am].s = *(const short8*)&As[(am * 32 + l31) * 256 + cc];
      }
      if (ks + 2 < 32) {                     // B lookahead depth 2 (global)
#pragma unroll
        for (int tj = 0; tj < 2; ++tj)
          b[(ks + 2) % 3][tj].s = *(const short8*)(bb + ((ks + 2) * 16 + tj) * 512);
      }
#pragma unroll
      for (int am = 0; am < 4; ++am)
#pragma unroll
        for (int tj = 0; tj < 2; ++tj)
          acc[am][tj] = __builtin_amdgcn_mfma_f32_32x32x16_bf16(
              a[cur][am].b, b[ks % 3][tj].b, acc[am][tj], 0, 0, 0);
    }
    if (half == 0) __syncthreads();          // all reads done before restage
  }

  // ---- epilogue: partial over this block's 256 h; cross-wave psums; atomic ----
  float b1v[2], w2v[2];
#pragma unroll
  for (int tj = 0; tj < 2; ++tj) {
    const int h = (hz8 + wid * 2 + tj) * 32 + l31;  // C/D: col = lane&31
    b1v[tj] = b1[h];
    w2v[tj] = W2[h];
  }
  __syncthreads();
  float* psums = (float*)As;  // [128 pairs][4 waves]
#pragma unroll
  for (int am = 0; am < 4; ++am) {
#pragma unroll
    for (int r = 0; r < 16; ++r) {
      float s = fmaxf(acc[am][0][r] + b1v[0], 0.f) * w2v[0] +
                fmaxf(acc[am][1][r] + b1v[1], 0.f) * w2v[1];
      s += __shfl_xor(s, 1, 64);
      s += __shfl_xor(s, 2, 64);
      s += __shfl_xor(s, 4, 64);
      s += __shfl_xor(s, 8, 64);
      s += __shfl_xor(s, 16, 64);
      if (l31 == 0) {
        const int row32 = (r & 3) + 8 * (r >> 2) + 4 * khalf;  // C/D row map
        psums[(am * 32 + row32) * 4 + wid] = s;
      }
    }
  }
  __syncthreads();
  if (tid < 128) {
    const float v = psums[tid * 4] + psums[tid * 4 + 1] +
                    psums[tid * 4 + 2] + psums[tid * 4 + 3];
    atomicAdd(out + (n0 + (tid >> 4)) * M_S + m0 + (tid & 15), v);
  }
}

__global__ __launch_bounds__(256) void logits_finalize(float* __restrict__ out,
                                                       const float* __restrict__ b2) {
  const int i = blockIdx.x * 256 + threadIdx.x;
  const float t = out[i] + b2[0];
  out[i] = 1.f / (1.f + __expf(-t));
}

extern "C" void kernel_launch(void* const* d_in, const int* in_sizes, int n_in,
                              void* d_out, int out_size, void* d_ws, size_t ws_size,
                              hipStream_t stream) {
  const float* emb = (const float*)d_in[0];
  const float* sup = (const float*)d_in[1];
  const float* W1  = (const float*)d_in[2];
  const float* b1  = (const float*)d_in[3];
  const float* W2  = (const float*)d_in[4];
  const float* b2  = (const float*)d_in[5];
  float* out = (float*)d_out;
  unsigned short* w1s = (unsigned short*)d_ws;  // 512 KB fragment-ordered W1

  prep_w1s<<<512, 512, 0, stream>>>(W1, w1s);
  hipMemsetAsync(d_out, 0, (size_t)N_Q * M_S * sizeof(float), stream);
  support_kernel<<<dim3(M_S / 16, N_Q / 8, 2), 256, 0, stream>>>(
      emb, sup, w1s, b1, W2, out);
  logits_finalize<<<(N_Q * M_S) / 256, 256, 0, stream>>>(out, b2);
}

// Round 7
// 254.787 us; speedup vs baseline: 1.0968x; 1.0968x over previous
//
#include <hip/hip_runtime.h>
#include <hip/hip_bf16.h>

#define N_Q 256
#define M_S 1024
#define DD 512
#define HH 512

typedef __attribute__((ext_vector_type(8))) short short8;
typedef __attribute__((ext_vector_type(8))) __bf16 bf16x8;
typedef __attribute__((ext_vector_type(16))) float f32x16;
typedef __attribute__((ext_vector_type(2))) __bf16 bf16x2;

union U8 { short8 s; bf16x8 b; };

__device__ __forceinline__ unsigned short f2bf(float f) {
  unsigned int u = __float_as_uint(f);
  u += 0x7FFFu + ((u >> 16) & 1u);
  return (unsigned short)(u >> 16);
}

__device__ __forceinline__ short8 pack8(const float* d) {
#if defined(__has_builtin) && __has_builtin(__builtin_amdgcn_cvt_pk_bf16_f32)
  short8 r;
#pragma unroll
  for (int i = 0; i < 4; ++i) {
    union { bf16x2 v; short s[2]; } u;
    u.v = __builtin_amdgcn_cvt_pk_bf16_f32(d[2 * i], d[2 * i + 1]);
    r[2 * i] = u.s[0];
    r[2 * i + 1] = u.s[1];
  }
  return r;
#else
  short8 r;
#pragma unroll
  for (int i = 0; i < 8; ++i) r[i] = (short)f2bf(d[i]);
  return r;
#endif
}

__device__ __forceinline__ short8 packdiff(float4 e0, float4 e1, float4 s0, float4 s1) {
  float d[8];
  d[0] = fabsf(e0.x - s0.x); d[1] = fabsf(e0.y - s0.y);
  d[2] = fabsf(e0.z - s0.z); d[3] = fabsf(e0.w - s0.w);
  d[4] = fabsf(e1.x - s1.x); d[5] = fabsf(e1.y - s1.y);
  d[6] = fabsf(e1.z - s1.z); d[7] = fabsf(e1.w - s1.w);
  return pack8(d);
}

// W1 [D][H] fp32 -> w1s in MFMA-B-fragment order (verified R3-R5).
// Frag f = kc*16 + h32; elem (lane l, j) = W1[kc*16 + (l>>5)*8 + j][h32*32 + (l&31)].
__global__ __launch_bounds__(512) void prep_w1s(const float* __restrict__ W1,
                                                unsigned short* __restrict__ w1s) {
  const int f = blockIdx.x;            // 0..511
  const int kc = f >> 4, h32 = f & 15;
  const int l = threadIdx.x & 63, j = threadIdx.x >> 6;
  const int h = h32 * 32 + (l & 31);
  const int k = kc * 16 + (l >> 5) * 8 + j;
  w1s[f * 512 + l * 8 + j] = f2bf(W1[k * HH + h]);
}

// Block: 256 thr = 4 waves, each 64p x 64h => acc[2][2] = 64 AGPR (reg diet ->
// 3 waves/SIMD). Block tile: 64 pairs x full H (hs-loop over two 256-h slices,
// partial logits in registers -> no atomics). A tile 64p x 256k in LDS,
// chunk-major [c][p] stride-65 (read conflict-free), restaged per (hs,kh).
// B register-direct from w1s with depth-2 lookahead.
__global__ __launch_bounds__(256, 3) void support_kernel(
    const float* __restrict__ emb, const float* __restrict__ sup,
    const unsigned short* __restrict__ w1s, const float* __restrict__ b1,
    const float* __restrict__ W2, const float* __restrict__ b2,
    float* __restrict__ out) {
  __shared__ short8 As16[32 * 65];   // [chunk c 0..31][p 0..63], 33280 B
  __shared__ float psums[64 * 4];

  const int tid = threadIdx.x;
  const int lane = tid & 63;
  const int wid = tid >> 6;          // 0..3 : 64-h slice within the hs half
  const int l31 = lane & 31;
  const int khalf = lane >> 5;

  const int m0 = blockIdx.x * 16;
  const int n0 = blockIdx.y * 4;

  // staging map: c = 16B k-chunk (0..31), grp = tid>>5: nl = grp>>1, mh = grp&1
  const int c = tid & 31;
  const int grp = tid >> 5;
  const int nl = grp >> 1;
  const int mh = grp & 1;
  const float* ep_ = emb + (n0 + nl) * DD + c * 8;
  const float* sp_ = sup + (m0 + mh * 8) * DD + c * 8;
  const int pbase = nl * 16 + mh * 8;

  float tpart = 0.f;  // running logit partial (meaningful for tid<64)

#pragma unroll 1
  for (int hs = 0; hs < 2; ++hs) {
    f32x16 acc[2][2] = {};
    // B fragment base for this hs: h32 = hs*8 + wid*2 + tj
    const unsigned short* bb = w1s + (hs * 8 + wid * 2) * 512 + lane * 8;

#pragma unroll
    for (int kh = 0; kh < 2; ++kh) {
      const int ksb = kh * 16;  // global 16-k step base of this segment
      U8 b[3][2];
      // B prologue: steps 0,1 of segment — issue BEFORE barrier/staging
#pragma unroll
      for (int tj = 0; tj < 2; ++tj) {
        b[0][tj].s = *(const short8*)(bb + ((ksb + 0) * 16 + tj) * 512);
        b[1][tj].s = *(const short8*)(bb + ((ksb + 1) * 16 + tj) * 512);
      }
      __syncthreads();  // prior As reads complete
      // ---- stage 64p x 256k diffs, chunk-major ----
      {
        const float4 e0 = *(const float4*)(ep_ + kh * 256);
        const float4 e1 = *(const float4*)(ep_ + kh * 256 + 4);
#pragma unroll
        for (int j = 0; j < 8; ++j) {
          const float* sp = sp_ + j * DD + kh * 256;
          const float4 s0 = *(const float4*)sp;
          const float4 s1 = *(const float4*)(sp + 4);
          As16[c * 65 + pbase + j] = packdiff(e0, e1, s0, s1);
        }
      }
      __syncthreads();  // tile visible

      U8 a[2][2];
#pragma unroll
      for (int am = 0; am < 2; ++am)
        a[0][am].s = As16[khalf * 65 + am * 32 + l31];  // kc=0 chunk

#pragma unroll
      for (int kc = 0; kc < 16; ++kc) {
        const int cur = kc & 1;
        if (kc < 15) {  // A lookahead depth 1 (LDS)
#pragma unroll
          for (int am = 0; am < 2; ++am)
            a[cur ^ 1][am].s = As16[((kc + 1) * 2 + khalf) * 65 + am * 32 + l31];
        }
        if (kc + 2 < 16) {  // B lookahead depth 2 (global/L2)
#pragma unroll
          for (int tj = 0; tj < 2; ++tj)
            b[(kc + 2) % 3][tj].s =
                *(const short8*)(bb + ((ksb + kc + 2) * 16 + tj) * 512);
        }
#pragma unroll
        for (int am = 0; am < 2; ++am)
#pragma unroll
          for (int tj = 0; tj < 2; ++tj)
            acc[am][tj] = __builtin_amdgcn_mfma_f32_32x32x16_bf16(
                a[cur][am].b, b[kc % 3][tj].b, acc[am][tj], 0, 0, 0);
      }
    }

    // ---- hs epilogue: s = sum_{64 h} relu(C+b1)*W2 -> psums -> tpart ----
    float b1v[2], w2v[2];
#pragma unroll
    for (int tj = 0; tj < 2; ++tj) {
      const int h = (hs * 8 + wid * 2 + tj) * 32 + l31;  // C/D col = lane&31
      b1v[tj] = b1[h];
      w2v[tj] = W2[h];
    }
#pragma unroll
    for (int am = 0; am < 2; ++am) {
#pragma unroll
      for (int r = 0; r < 16; ++r) {
        float s = fmaxf(acc[am][0][r] + b1v[0], 0.f) * w2v[0] +
                  fmaxf(acc[am][1][r] + b1v[1], 0.f) * w2v[1];
        s += __shfl_xor(s, 1, 64);
        s += __shfl_xor(s, 2, 64);
        s += __shfl_xor(s, 4, 64);
        s += __shfl_xor(s, 8, 64);
        s += __shfl_xor(s, 16, 64);
        if (l31 == 0) {
          const int row32 = (r & 3) + 8 * (r >> 2) + 4 * khalf;  // C/D row map
          psums[(am * 32 + row32) * 4 + wid] = s;
        }
      }
    }
    __syncthreads();
    if (tid < 64)
      tpart += psums[tid * 4] + psums[tid * 4 + 1] +
               psums[tid * 4 + 2] + psums[tid * 4 + 3];
    // next psums write is ordered behind the kh-loop barriers of hs+1
  }

  if (tid < 64) {
    const float t = tpart + b2[0];
    out[(n0 + (tid >> 4)) * M_S + m0 + (tid & 15)] = 1.f / (1.f + __expf(-t));
  }
}

extern "C" void kernel_launch(void* const* d_in, const int* in_sizes, int n_in,
                              void* d_out, int out_size, void* d_ws, size_t ws_size,
                              hipStream_t stream) {
  const float* emb = (const float*)d_in[0];
  const float* sup = (const float*)d_in[1];
  const float* W1  = (const float*)d_in[2];
  const float* b1  = (const float*)d_in[3];
  const float* W2  = (const float*)d_in[4];
  const float* b2  = (const float*)d_in[5];
  float* out = (float*)d_out;
  unsigned short* w1s = (unsigned short*)d_ws;  // 512 KB fragment-ordered W1

  prep_w1s<<<512, 512, 0, stream>>>(W1, w1s);
  support_kernel<<<dim3(M_S / 16, N_Q / 4), 256, 0, stream>>>(
      emb, sup, w1s, b1, W2, b2, out);
}

// Round 8
// 230.612 us; speedup vs baseline: 1.2117x; 1.1048x over previous
//
#include <hip/hip_runtime.h>
#include <hip/hip_bf16.h>

#define N_Q 256
#define M_S 1024
#define DD 512
#define HH 512

typedef __attribute__((ext_vector_type(8))) short short8;
typedef __attribute__((ext_vector_type(8))) __bf16 bf16x8;
typedef __attribute__((ext_vector_type(16))) float f32x16;
typedef __attribute__((ext_vector_type(2))) __bf16 bf16x2;

union U8 { short8 s; bf16x8 b; };

__device__ __forceinline__ unsigned short f2bf(float f) {
  unsigned int u = __float_as_uint(f);
  u += 0x7FFFu + ((u >> 16) & 1u);
  return (unsigned short)(u >> 16);
}

__device__ __forceinline__ short8 pack8(const float* d) {
#if defined(__has_builtin) && __has_builtin(__builtin_amdgcn_cvt_pk_bf16_f32)
  short8 r;
#pragma unroll
  for (int i = 0; i < 4; ++i) {
    union { bf16x2 v; short s[2]; } u;
    u.v = __builtin_amdgcn_cvt_pk_bf16_f32(d[2 * i], d[2 * i + 1]);
    r[2 * i] = u.s[0];
    r[2 * i + 1] = u.s[1];
  }
  return r;
#else
  short8 r;
#pragma unroll
  for (int i = 0; i < 8; ++i) r[i] = (short)f2bf(d[i]);
  return r;
#endif
}

__device__ __forceinline__ short8 packdiff(float4 e0, float4 e1, float4 s0, float4 s1) {
  float d[8];
  d[0] = fabsf(e0.x - s0.x); d[1] = fabsf(e0.y - s0.y);
  d[2] = fabsf(e0.z - s0.z); d[3] = fabsf(e0.w - s0.w);
  d[4] = fabsf(e1.x - s1.x); d[5] = fabsf(e1.y - s1.y);
  d[6] = fabsf(e1.z - s1.z); d[7] = fabsf(e1.w - s1.w);
  return pack8(d);
}

// W1 [D][H] fp32 -> w1s in MFMA-B-fragment order (verified R3-R7).
// Frag f = kc*16 + h32; elem (lane l, j) = W1[kc*16 + (l>>5)*8 + j][h32*32 + (l&31)].
__global__ __launch_bounds__(512) void prep_w1s(const float* __restrict__ W1,
                                                unsigned short* __restrict__ w1s) {
  const int f = blockIdx.x;            // 0..511
  const int kc = f >> 4, h32 = f & 15;
  const int l = threadIdx.x & 63, j = threadIdx.x >> 6;
  const int h = h32 * 32 + (l & 31);
  const int k = kc * 16 + (l >> 5) * 8 + j;
  w1s[f * 512 + l * 8 + j] = f2bf(W1[k * HH + h]);
}

// Block: 512 thr = 8 waves. Tile 64 pairs x 512 h x full K=512.
// A (diff) staged ONCE into exactly 64 KB LDS, layout [p][c ^ (p&7)] in 16B
// chunks (writes and reads both <=2-way bank aliased = free). Each wave:
// 64p x 64h -> acc[2][2] = 64 AGPR; B register-direct from w1s, depth-2
// lookahead. Target: <=128 total regs/wave -> 4 waves/SIMD, 16 waves/CU.
// 3 barriers per block.
__global__ __launch_bounds__(512, 4) void support_kernel(
    const float* __restrict__ emb, const float* __restrict__ sup,
    const unsigned short* __restrict__ w1s, const float* __restrict__ b1,
    const float* __restrict__ W2, const float* __restrict__ b2,
    float* __restrict__ out) {
  __shared__ short8 As16[64 * 64];   // [p 0..63][chunk' 0..63], 65536 B exactly

  const int tid = threadIdx.x;
  const int lane = tid & 63;
  const int wid = tid >> 6;          // 0..7 : 64-h slice (h32 base = wid*2)
  const int l31 = lane & 31;
  const int khalf = lane >> 5;

  const int m0 = blockIdx.x * 16;
  const int n0 = blockIdx.y * 4;

  // ---- staging map: c = 16B k-chunk (0..63), rg = tid>>6 -> 8 rows each ----
  const int c = tid & 63;
  const int rg = tid >> 6;           // == wid (wave-uniform)
  const int nl = rg >> 1;
  const int mq = rg & 1;

  // B prologue for ks=0,1 issued BEFORE staging (overlaps with it)
  const unsigned short* bb = w1s + (wid * 2) * 512 + lane * 8;
  U8 b[3][2];
#pragma unroll
  for (int tj = 0; tj < 2; ++tj) {
    b[0][tj].s = *(const short8*)(bb + (0 * 16 + tj) * 512);
    b[1][tj].s = *(const short8*)(bb + (1 * 16 + tj) * 512);
  }

  // ---- stage 64p x 512k diffs (once) ----
  {
    const float* ep = emb + (n0 + nl) * DD + c * 8;
    const float4 e0 = *(const float4*)ep;
    const float4 e1 = *(const float4*)(ep + 4);
    const float* sbase = sup + (m0 + mq * 8) * DD + c * 8;
#pragma unroll
    for (int j = 0; j < 8; ++j) {
      const float4 s0 = *(const float4*)(sbase + j * DD);
      const float4 s1 = *(const float4*)(sbase + j * DD + 4);
      const int p = rg * 8 + j;                 // p&7 == j
      As16[p * 64 + (c ^ j)] = packdiff(e0, e1, s0, s1);
    }
  }
  __syncthreads();  // barrier 1: tile visible

  // ---- barrier-free K-loop: 32 steps of 16 k ----
  const int ar0 = (0 + l31) * 64;    // A row base, am=0 (short8 units)
  const int ar1 = (32 + l31) * 64;
  const int ax = l31 & 7;            // read-side chunk XOR (p&7 == l31&7)

  f32x16 acc[2][2] = {};
  U8 a[2][2];
  a[0][0].s = As16[ar0 + (khalf ^ ax)];
  a[0][1].s = As16[ar1 + (khalf ^ ax)];

#pragma unroll
  for (int ks = 0; ks < 32; ++ks) {
    const int cur = ks & 1;
    if (ks < 31) {  // A lookahead depth 1 (LDS)
      const int cc = ((ks + 1) * 2 + khalf) ^ ax;
      a[cur ^ 1][0].s = As16[ar0 + cc];
      a[cur ^ 1][1].s = As16[ar1 + cc];
    }
    if (ks + 2 < 32) {  // B lookahead depth 2 (global/L2)
#pragma unroll
      for (int tj = 0; tj < 2; ++tj)
        b[(ks + 2) % 3][tj].s = *(const short8*)(bb + ((ks + 2) * 16 + tj) * 512);
    }
#pragma unroll
    for (int am = 0; am < 2; ++am)
#pragma unroll
      for (int tj = 0; tj < 2; ++tj)
        acc[am][tj] = __builtin_amdgcn_mfma_f32_32x32x16_bf16(
            a[cur][am].b, b[ks % 3][tj].b, acc[am][tj], 0, 0, 0);
  }

  // ---- epilogue: s = sum_{64 h} relu(C+b1)*W2; cross-wave psums reduce ----
  float b1v[2], w2v[2];
#pragma unroll
  for (int tj = 0; tj < 2; ++tj) {
    const int h = (wid * 2 + tj) * 32 + l31;   // C/D: col = lane&31
    b1v[tj] = b1[h];
    w2v[tj] = W2[h];
  }
  __syncthreads();  // barrier 2: all As16 reads done before aliasing
  float* psums = (float*)As16;  // [64 pairs][8 waves]
#pragma unroll
  for (int am = 0; am < 2; ++am) {
#pragma unroll
    for (int r = 0; r < 16; ++r) {
      float s = fmaxf(acc[am][0][r] + b1v[0], 0.f) * w2v[0] +
                fmaxf(acc[am][1][r] + b1v[1], 0.f) * w2v[1];
      s += __shfl_xor(s, 1, 64);
      s += __shfl_xor(s, 2, 64);
      s += __shfl_xor(s, 4, 64);
      s += __shfl_xor(s, 8, 64);
      s += __shfl_xor(s, 16, 64);
      if (l31 == 0) {
        const int row32 = (r & 3) + 8 * (r >> 2) + 4 * khalf;  // C/D row map
        psums[(am * 32 + row32) * 8 + wid] = s;
      }
    }
  }
  __syncthreads();  // barrier 3
  if (tid < 64) {
    float t = b2[0];
#pragma unroll
    for (int w = 0; w < 8; ++w) t += psums[tid * 8 + w];
    out[(n0 + (tid >> 4)) * M_S + m0 + (tid & 15)] = 1.f / (1.f + __expf(-t));
  }
}

extern "C" void kernel_launch(void* const* d_in, const int* in_sizes, int n_in,
                              void* d_out, int out_size, void* d_ws, size_t ws_size,
                              hipStream_t stream) {
  const float* emb = (const float*)d_in[0];
  const float* sup = (const float*)d_in[1];
  const float* W1  = (const float*)d_in[2];
  const float* b1  = (const float*)d_in[3];
  const float* W2  = (const float*)d_in[4];
  const float* b2  = (const float*)d_in[5];
  float* out = (float*)d_out;
  unsigned short* w1s = (unsigned short*)d_ws;  // 512 KB fragment-ordered W1

  prep_w1s<<<512, 512, 0, stream>>>(W1, w1s);
  support_kernel<<<dim3(M_S / 16, N_Q / 4), 512, 0, stream>>>(
      emb, sup, w1s, b1, W2, b2, out);
}